// Round 15
// baseline (368.023 us; speedup 1.0000x reference)
//
#include <hip/hip_runtime.h>
#include <hip/hip_bf16.h>
#include <float.h>

#define BB 4
#define SS 2048
#define DD 1024
#define HH 16
#define DP 64
#define BKS 32
#define MARGIN_F 0.025f  /* >= 2x(packing 3.9e-3 + 2-pass filter 3sig 2.2e-3) */
#define TIER2_TAU 1e-4   /* recon-gap below this -> ground-truth re-adjudication */

typedef __attribute__((ext_vector_type(8))) _Float16 half8v;
typedef __attribute__((ext_vector_type(16))) float f32x16;

typedef __attribute__((address_space(3))) void lds_void;
typedef const __attribute__((address_space(1))) void gbl_void;
static __device__ __forceinline__ void gload16(const void* g, void* l) {
  __builtin_amdgcn_global_load_lds((gbl_void*)g, (lds_void*)l, 16, 0, 0);
}

// ---------------------------------------------------------------------------
// xcast: one-shot x fp32 -> fp16 hi/lo split (removes 24x-redundant per-K-step
// VALU split from proj's A staging).
// ---------------------------------------------------------------------------
__global__ __launch_bounds__(256) void xcast_kernel(
    const float* __restrict__ x, _Float16* __restrict__ xh,
    _Float16* __restrict__ xl)
{
  const size_t e0 = ((size_t)blockIdx.x * 256 + threadIdx.x) * 8;
  const float4 v0 = *(const float4*)(x + e0);
  const float4 v1 = *(const float4*)(x + e0 + 4);
  const float xv[8] = {v0.x, v0.y, v0.z, v0.w, v1.x, v1.y, v1.z, v1.w};
  half8v h, l;
  #pragma unroll
  for (int j = 0; j < 8; ++j) {
    h[j] = (_Float16)xv[j];
    l[j] = (_Float16)(xv[j] - (float)h[j]);
  }
  *(half8v*)(xh + e0) = h;
  *(half8v*)(xl + e0) = l;
}

// ---------------------------------------------------------------------------
// Prep: transpose W[k][n] f32 -> Wt[n][k] fp16 hi (+ fp16 lo for Wq,Wk).
// z = blockIdx.z + zofs: 0=Wq(hi+lo) 1=Wk(hi+lo) 2=Wv(hi) 3=Wo(hi).
// ---------------------------------------------------------------------------
__global__ __launch_bounds__(256) void wtrans_kernel(
    const float* __restrict__ Wq, const float* __restrict__ Wk,
    const float* __restrict__ Wv, const float* __restrict__ Wo,
    _Float16* __restrict__ Wqh, _Float16* __restrict__ Wql,
    _Float16* __restrict__ Wkh, _Float16* __restrict__ Wkl,
    _Float16* __restrict__ Wvh, _Float16* __restrict__ Woh, int zofs)
{
  const int z = blockIdx.z + zofs;
  const float* __restrict__ src = (z == 0) ? Wq : (z == 1 ? Wk : (z == 2 ? Wv : Wo));
  _Float16* __restrict__ dh = (z == 0) ? Wqh : (z == 1 ? Wkh : (z == 2 ? Wvh : Woh));
  _Float16* __restrict__ dl = (z == 0) ? Wql : Wkl;
  __shared__ float tile[64][65];
  const int k0 = blockIdx.x * 64, n0 = blockIdx.y * 64;
  const int c = threadIdx.x & 63, rb = threadIdx.x >> 6;
  #pragma unroll
  for (int i = 0; i < 16; ++i)
    tile[rb + 4 * i][c] = src[(size_t)(k0 + rb + 4 * i) * DD + n0 + c];
  __syncthreads();
  #pragma unroll
  for (int i = 0; i < 16; ++i) {
    const int n = n0 + rb + 4 * i;
    const float v = tile[c][rb + 4 * i];
    const _Float16 h = (_Float16)v;
    dh[(size_t)n * DD + k0 + c] = h;
    if (z < 2) dl[(size_t)n * DD + k0 + c] = (_Float16)(v - (float)h);
  }
}

// ---------------------------------------------------------------------------
// LDS-staged fp16 MFMA projection GEMM, 3-pass split.  BOTH operands now
// staged via global_load_lds (A from precomputed xh/xl with the same
// interleaved inverse-XOR source permutation as B).  z = blockIdx.z + zofs.
// ---------------------------------------------------------------------------
__global__ __launch_bounds__(256) void proj_mfma(
    const _Float16* __restrict__ xh, const _Float16* __restrict__ xl,
    const _Float16* __restrict__ Wqh, const _Float16* __restrict__ Wql,
    const _Float16* __restrict__ Wkh, const _Float16* __restrict__ Wkl,
    const _Float16* __restrict__ Wvh,
    _Float16* __restrict__ Qhi, _Float16* __restrict__ Qlo,
    _Float16* __restrict__ Khi, _Float16* __restrict__ Klo,
    _Float16* __restrict__ Vh, int zofs)
{
  const int z = blockIdx.z + zofs;
  const bool split = (z < 2);
  const _Float16* __restrict__ Wh = (z == 0) ? Wqh : (z == 1 ? Wkh : Wvh);
  const _Float16* __restrict__ Wl = (z == 0) ? Wql : Wkl;
  _Float16* __restrict__ dhi = (z == 0) ? Qhi : (z == 1 ? Khi : Vh);
  _Float16* __restrict__ dlo = (z == 0) ? Qlo : Klo;

  __shared__ _Float16 Asm[8192];
  __shared__ _Float16 Bsm[8192];

  const int rows0 = blockIdx.x * 128, cols0 = blockIdx.y * 128;
  const int t = threadIdx.x;
  const int wid = t >> 6, l = t & 63;
  const int warpR = wid >> 1, warpC = wid & 1;
  const int lr = l & 31, lh = l >> 5;

  f32x16 acc[2][2];
  #pragma unroll
  for (int i = 0; i < 2; ++i)
    #pragma unroll
    for (int j = 0; j < 2; ++j)
      #pragma unroll
      for (int r = 0; r < 16; ++r) acc[i][j][r] = 0.f;

  const int nbi = split ? 4 : 2;
  const _Float16* asrc[4];
  const _Float16* bsrc[4];
  #pragma unroll
  for (int i = 0; i < 4; ++i) {
    const int s = t + i * 256;
    if (split) {
      const int row = s >> 3;
      const int u = (s & 7) ^ (row & 7);
      asrc[i] = ((u & 1) ? xl : xh) + (size_t)(rows0 + row) * DD + (u >> 1) * 8;
      bsrc[i] = ((u & 1) ? Wl : Wh) + (size_t)(cols0 + row) * DD + (u >> 1) * 8;
    } else {
      const int row = (s & 511) >> 2;
      const int csrc = (s & 3) ^ ((row >> 1) & 3);
      asrc[i] = xh + (size_t)(rows0 + row) * DD + csrc * 8;
      bsrc[i] = Wh + (size_t)(cols0 + row) * DD + csrc * 8;
    }
  }

  for (int ks = 0; ks < 32; ++ks) {
    const int k0 = ks * BKS;
    if (ks) __syncthreads();

    #pragma unroll
    for (int i = 0; i < 4; ++i)
      if (i < nbi) {
        gload16(asrc[i] + k0, &Asm[(t + i * 256) * 8]);
        gload16(bsrc[i] + k0, &Bsm[(t + i * 256) * 8]);
      }
    __syncthreads();

    #pragma unroll
    for (int kh2 = 0; kh2 < 2; ++kh2) {
      const int c = kh2 * 2 + lh;
      half8v ah[2], alv[2], bh[2], blv[2];
      #pragma unroll
      for (int wr = 0; wr < 2; ++wr) {
        const int row = warpR * 64 + wr * 32 + lr;
        if (split) {
          ah[wr]  = *(const half8v*)&Asm[(row * 8 + ((2 * c) ^ (row & 7))) * 8];
          alv[wr] = *(const half8v*)&Asm[(row * 8 + ((2 * c + 1) ^ (row & 7))) * 8];
        } else {
          ah[wr] = *(const half8v*)&Asm[(row * 4 + (c ^ ((row >> 1) & 3))) * 8];
        }
      }
      #pragma unroll
      for (int wc = 0; wc < 2; ++wc) {
        const int col = warpC * 64 + wc * 32 + lr;
        if (split) {
          bh[wc]  = *(const half8v*)&Bsm[(col * 8 + ((2 * c) ^ (col & 7))) * 8];
          blv[wc] = *(const half8v*)&Bsm[(col * 8 + ((2 * c + 1) ^ (col & 7))) * 8];
        } else {
          bh[wc] = *(const half8v*)&Bsm[(col * 4 + (c ^ ((col >> 1) & 3))) * 8];
        }
      }
      #pragma unroll
      for (int wr = 0; wr < 2; ++wr)
        #pragma unroll
        for (int wc = 0; wc < 2; ++wc) {
          acc[wr][wc] = __builtin_amdgcn_mfma_f32_32x32x16_f16(ah[wr], bh[wc], acc[wr][wc], 0, 0, 0);
          if (split) {
            acc[wr][wc] = __builtin_amdgcn_mfma_f32_32x32x16_f16(alv[wr], bh[wc], acc[wr][wc], 0, 0, 0);
            acc[wr][wc] = __builtin_amdgcn_mfma_f32_32x32x16_f16(ah[wr], blv[wc], acc[wr][wc], 0, 0, 0);
          }
        }
    }
  }

  const int mb0 = rows0 + warpR * 64 + 4 * lh;
  #pragma unroll
  for (int wr = 0; wr < 2; ++wr)
    #pragma unroll
    for (int wc = 0; wc < 2; ++wc) {
      const int n = cols0 + warpC * 64 + wc * 32 + lr;
      const int h = n >> 6, d = n & 63;
      #pragma unroll
      for (int r = 0; r < 16; ++r) {
        const int m = mb0 + wr * 32 + (r & 3) + 8 * (r >> 2);
        const int b = m >> 11, srow = m & 2047;
        const size_t o = ((size_t)(b * HH + h) * SS + srow) * DP + d;
        const float a = acc[wr][wc][r];
        const _Float16 h16 = (_Float16)a;
        dhi[o] = h16;
        if (split) dlo[o] = (_Float16)(a - (float)h16);
      }
    }
}

// ---------------------------------------------------------------------------
// Mask scan -> compact key list padded to x32 with duplicates of the first
// masked key; writes real count (for validity masking) and padded count.
// ---------------------------------------------------------------------------
__global__ __launch_bounds__(256) void scan_kernel(
    const int* __restrict__ mask, int* __restrict__ klist,
    int* __restrict__ cntpad, int* __restrict__ cntreal)
{
  __shared__ int part[256];
  __shared__ int tot;
  const int b = blockIdx.x, t = threadIdx.x;
  int loc[8]; int c = 0;
  #pragma unroll
  for (int j = 0; j < 8; ++j) {
    loc[j] = (mask[(b << 11) + t * 8 + j] == 0);
    c += loc[j];
  }
  part[t] = c;
  __syncthreads();
  if (t == 0) {
    int run = 0;
    for (int i = 0; i < 256; ++i) { int v = part[i]; part[i] = run; run += v; }
    tot = run;
  }
  __syncthreads();
  int off = part[t];
  #pragma unroll
  for (int j = 0; j < 8; ++j)
    if (loc[j]) klist[(b << 11) + off++] = t * 8 + j;
  __syncthreads();
  if (t == 0) {
    int n = tot;
    int first;
    if (n == 0) { klist[b << 11] = 0; n = 1; first = 0; }
    else first = klist[b << 11];
    int np = (n + 31) & ~31;
    for (int i = n; i < np; ++i) klist[(b << 11) + i] = first;
    cntpad[b] = np;
    cntreal[b] = n;
  }
}

// ---------------------------------------------------------------------------
// MFMA masked-argmin filter, 2-pass, LDS-staged Khi, top-4 (r14 version).
// ---------------------------------------------------------------------------
__global__ __launch_bounds__(256) void filter_kernel(
    const _Float16* __restrict__ Qhi, const _Float16* __restrict__ Qlo,
    const _Float16* __restrict__ Khi,
    const int* __restrict__ klist, const int* __restrict__ cntpad,
    const int* __restrict__ cntreal,
    int* __restrict__ idx, int* __restrict__ ambr, int* __restrict__ ambc,
    int* __restrict__ cand, int* __restrict__ ccnt)
{
  __shared__ _Float16 Ksm[2048];   // 4 KB
  const int bh = blockIdx.x >> 4;
  const int b = bh >> 4;
  const int wid = threadIdx.x >> 6;
  const int t = threadIdx.x;
  const int l = t & 63;
  const int q0 = ((blockIdx.x & 15) << 7) + (wid << 5);
  const int half = l >> 5;
  const int lq = l & 31;
  const int* __restrict__ kl_b = klist + (b << 11);

  half8v qh[4], ql[4];
  {
    const size_t qrow = ((size_t)bh * SS + q0 + lq) * DP + half * 8;
    #pragma unroll
    for (int ds = 0; ds < 4; ++ds) {
      qh[ds] = *(const half8v*)(Qhi + qrow + ds * 16);
      ql[ds] = *(const half8v*)(Qlo + qrow + ds * 16);
    }
  }

  const int srow = t >> 3;
  const int sslot = t & 7;
  const int scc = sslot ^ (srow & 7);

  const int nreal = cntreal[b];
  const int nt = cntpad[b] >> 5;
  float m1 = FLT_MAX, m2 = FLT_MAX, m3 = FLT_MAX, m4 = FLT_MAX;
  uint kidx[16];
  #pragma unroll
  for (int r = 0; r < 16; ++r)
    kidx[r] = (uint)((r & 3) + ((r >> 2) << 3) + (half << 2));

  const size_t kbase = (size_t)bh * SS;
  for (int kt = 0; kt < nt; ++kt) {
    if (kt) __syncthreads();
    {
      const int kval = kl_b[(kt << 5) + srow];
      gload16(Khi + (kbase + kval) * DP + scc * 8, &Ksm[t * 8]);
    }
    __syncthreads();

    f32x16 acc;
    #pragma unroll
    for (int r = 0; r < 16; ++r) acc[r] = 0.f;
    #pragma unroll
    for (int ds = 0; ds < 4; ++ds) {
      const int cc = ds * 2 + half;
      const int sl = lq * 8 + (cc ^ (lq & 7));
      const half8v kh = *(const half8v*)&Ksm[sl * 8];
      acc = __builtin_amdgcn_mfma_f32_32x32x16_f16(kh, qh[ds], acc, 0, 0, 0);
      acc = __builtin_amdgcn_mfma_f32_32x32x16_f16(kh, ql[ds], acc, 0, 0, 0);
    }
    const bool part = (kt == nt - 1) && ((nreal & 31) != 0);
    #pragma unroll
    for (int r = 0; r < 16; ++r) {
      const uint pv = (__float_as_uint(acc[r]) & 0xFFFFF800u) | kidx[r];
      float v = __uint_as_float(pv);
      if (part && kidx[r] >= (uint)nreal) v = FLT_MAX;
      m4 = __builtin_amdgcn_fmed3f(v, m3, m4);
      m3 = __builtin_amdgcn_fmed3f(v, m2, m3);
      m2 = __builtin_amdgcn_fmed3f(v, m1, m2);
      m1 = fminf(v, m1);
      kidx[r] += 32;
    }
  }

  float om[4];
  om[0] = __shfl_xor(m1, 32, 64);
  om[1] = __shfl_xor(m2, 32, 64);
  om[2] = __shfl_xor(m3, 32, 64);
  om[3] = __shfl_xor(m4, 32, 64);
  #pragma unroll
  for (int j = 0; j < 4; ++j) {
    const float v = om[j];
    m4 = __builtin_amdgcn_fmed3f(v, m3, m4);
    m3 = __builtin_amdgcn_fmed3f(v, m2, m3);
    m2 = __builtin_amdgcn_fmed3f(v, m1, m2);
    m1 = fminf(v, m1);
  }

  if (half == 0) {
    const int row = bh * SS + q0 + lq;
    const uint u1 = __float_as_uint(m1);
    const int k1 = kl_b[u1 & 2047u];
    idx[row] = k1;
    const float v1 = __uint_as_float(u1 & 0xFFFFF800u);
    const uint us[3] = {__float_as_uint(m2), __float_as_uint(m3),
                        __float_as_uint(m4)};
    const float v2 = __uint_as_float(us[0] & 0xFFFFF800u);
    if (v2 - v1 < MARGIN_F) {
      int c[4]; int n = 0;
      c[n++] = k1;
      #pragma unroll
      for (int j = 0; j < 3; ++j) {
        const float vj = __uint_as_float(us[j] & 0xFFFFF800u);
        if (vj - v1 < MARGIN_F) c[n++] = kl_b[us[j] & 2047u];
        else break;
      }
      const int pos = atomicAdd(ambc, 1);
      ambr[pos] = row;
      ccnt[row] = n;
      for (int j = 0; j < n; ++j) cand[row * 8 + j] = c[j];
    }
  }
}

// ---------------------------------------------------------------------------
// Two-tier refine (r9/r10 version, verbatim).
// ---------------------------------------------------------------------------
__global__ __launch_bounds__(256) void refine_kernel(
    const _Float16* __restrict__ Qhi, const _Float16* __restrict__ Qlo,
    const _Float16* __restrict__ Khi, const _Float16* __restrict__ Klo,
    const float* __restrict__ x, const float* __restrict__ Wq,
    const float* __restrict__ Wk,
    const int* __restrict__ ambr, const int* __restrict__ ambc,
    const int* __restrict__ cand, const int* __restrict__ ccnt,
    int* __restrict__ idx)
{
  __shared__ double red[4][7][64];
  const int n = *ambc;
  const int t = threadIdx.x;
  const int w = t >> 6, lane = t & 63;

  for (int it = blockIdx.x; it < n; it += gridDim.x) {
    const int row = ambr[it];
    const int bh = row >> 11;
    const int cnum = ccnt[row];

    const size_t qb = (size_t)row * DP;
    const double q = (double)(float)Qhi[qb + lane] + (double)(float)Qlo[qb + lane];
    double best = 1e300, best2 = 1e300; int bi = 0x7fffffff;
    for (int c = 0; c < cnum; ++c) {
      const int k = cand[row * 8 + c] & 2047;
      const size_t kb = ((size_t)bh * SS + k) * DP;
      const double kv = (double)(float)Khi[kb + lane] + (double)(float)Klo[kb + lane];
      double p = q * kv;
      #pragma unroll
      for (int o = 32; o > 0; o >>= 1) p += __shfl_xor(p, o, 64);
      if (p < best) { best2 = best; best = p; bi = k; }
      else if (p < best2) best2 = p;
    }

    if (best2 - best < TIER2_TAU) {
      const int qq = row & 2047;
      const int b = bh >> 4, h = bh & 15;
      const int wc = (h << 6) + lane;
      const float* xq = x + ((size_t)(b << 11) + qq) * DD;
      int kk[6];
      #pragma unroll
      for (int c = 0; c < 6; ++c)
        kk[c] = cand[row * 8 + (c < cnum ? c : 0)] & 2047;
      const float* xk0 = x + ((size_t)(b << 11) + kk[0]) * DD;
      const float* xk1 = x + ((size_t)(b << 11) + kk[1]) * DD;
      const float* xk2 = x + ((size_t)(b << 11) + kk[2]) * DD;
      const float* xk3 = x + ((size_t)(b << 11) + kk[3]) * DD;
      const float* xk4 = x + ((size_t)(b << 11) + kk[4]) * DD;
      const float* xk5 = x + ((size_t)(b << 11) + kk[5]) * DD;

      double qd = 0.0, kd0 = 0.0, kd1 = 0.0, kd2 = 0.0,
             kd3 = 0.0, kd4 = 0.0, kd5 = 0.0;
      const int j0 = w * 256;
      #pragma unroll 4
      for (int j = j0; j < j0 + 256; ++j) {
        const double wq = (double)Wq[(size_t)j * DD + wc];
        const double wk = (double)Wk[(size_t)j * DD + wc];
        qd  = fma((double)xq[j],  wq, qd);
        kd0 = fma((double)xk0[j], wk, kd0);
        kd1 = fma((double)xk1[j], wk, kd1);
        kd2 = fma((double)xk2[j], wk, kd2);
        kd3 = fma((double)xk3[j], wk, kd3);
        kd4 = fma((double)xk4[j], wk, kd4);
        kd5 = fma((double)xk5[j], wk, kd5);
      }
      red[w][0][lane] = qd;
      red[w][1][lane] = kd0; red[w][2][lane] = kd1; red[w][3][lane] = kd2;
      red[w][4][lane] = kd3; red[w][5][lane] = kd4; red[w][6][lane] = kd5;
      __syncthreads();

      if (w == 0) {
        const double qs = red[0][0][lane] + red[1][0][lane] +
                          red[2][0][lane] + red[3][0][lane];
        best = 1e300; bi = 0x7fffffff;
        for (int c = 0; c < cnum; ++c) {
          const double ks = red[0][1 + c][lane] + red[1][1 + c][lane] +
                            red[2][1 + c][lane] + red[3][1 + c][lane];
          double p = qs * ks;
          #pragma unroll
          for (int o = 32; o > 0; o >>= 1) p += __shfl_xor(p, o, 64);
          const int k = kk[c];
          if (p < best || (p == best && k < bi)) { best = p; bi = k; }
        }
        if (lane == 0) idx[row] = bi;
      }
      __syncthreads();
    } else {
      if (t == 0) idx[row] = bi;
    }
  }
}

// ---------------------------------------------------------------------------
// fp16 MFMA out-projection, LDS-staged B (r11/r12 version).
// ---------------------------------------------------------------------------
__global__ __launch_bounds__(256) void out_mfma(
    const _Float16* __restrict__ Vh, const int* __restrict__ idx,
    const _Float16* __restrict__ Woh, const float* __restrict__ bo,
    const float* __restrict__ gamma, const float* __restrict__ beta,
    const float* __restrict__ mmean, const float* __restrict__ mvar,
    float* __restrict__ out)
{
  __shared__ _Float16 Bsm[8192];
  const int rows0 = blockIdx.x * 128, cols0 = blockIdx.y * 128;
  const int t = threadIdx.x;
  const int w = t >> 6, l = t & 63;
  const int lr = l & 31, lh = l >> 5;
  const int hi8 = lh * 8;
  const int m = rows0 + w * 32 + lr;
  const int b = m >> 11, srow = m & 2047;

  const _Float16* bsrc[4];
  #pragma unroll
  for (int i = 0; i < 4; ++i) {
    const int s = t + i * 256;
    const int col = s >> 3;
    const int u = (s & 7) ^ (col & 7);
    bsrc[i] = Woh + (size_t)(cols0 + col) * DD + u * 8;
  }

  f32x16 acc[4];
  #pragma unroll
  for (int cf = 0; cf < 4; ++cf)
    #pragma unroll
    for (int r = 0; r < 16; ++r) acc[cf][r] = 0.f;

  for (int kt = 0; kt < 16; ++kt) {
    const int k0 = kt * 64;
    if (kt) __syncthreads();
    #pragma unroll
    for (int i = 0; i < 4; ++i)
      gload16(bsrc[i] + k0, &Bsm[(t + i * 256) * 8]);
    const int vi = idx[(size_t)(b * HH + kt) * SS + srow];
    const _Float16* arow = Vh + ((size_t)(b * HH + kt) * SS + vi) * DP;
    __syncthreads();

    #pragma unroll
    for (int ss = 0; ss < 4; ++ss) {
      half8v a = *(const half8v*)(arow + ss * 16 + hi8);
      const int cl = ss * 2 + lh;
      #pragma unroll
      for (int cf = 0; cf < 4; ++cf) {
        const int col = cf * 32 + lr;
        half8v bf = *(const half8v*)&Bsm[(col * 8 + (cl ^ (col & 7))) * 8];
        acc[cf] = __builtin_amdgcn_mfma_f32_32x32x16_f16(a, bf, acc[cf], 0, 0, 0);
      }
    }
  }

  const int m_base = rows0 + w * 32 + 4 * lh;
  #pragma unroll
  for (int cf = 0; cf < 4; ++cf) {
    const int n = cols0 + cf * 32 + lr;
    const float sc = gamma[n] * rsqrtf(mvar[n] + 1e-3f);
    const float ofs = (bo[n] - mmean[n]) * sc + beta[n];
    #pragma unroll
    for (int r = 0; r < 16; ++r) {
      const int mr = m_base + (r & 3) + 8 * (r >> 2);
      out[(size_t)mr * DD + n] = acc[cf][r] * sc + ofs;
    }
  }
}

// ---------------------------------------------------------------------------
// ws layout (total 106 MB, overlays are stream-ordered):
//   [0,16M):   xh  -> after proj: Woh(2M) + klist/cnt/idx/ambr/ambc/ccnt/cnd
//   [16M,32M): xl  -> after projQK: Vh (written by projV)
//   [32M,96M): Qhi, Qlo, Khi, Klo
//   [96M,106M): Wqh, Wql, Wkh, Wkl, Wvh
// ---------------------------------------------------------------------------
extern "C" void kernel_launch(void* const* d_in, const int* in_sizes, int n_in,
                              void* d_out, int out_size, void* d_ws, size_t ws_size,
                              hipStream_t stream)
{
  const float* x  = (const float*)d_in[0];
  const int* mask = (const int*)d_in[1];
  const float* Wq = (const float*)d_in[2];
  const float* Wk = (const float*)d_in[3];
  const float* Wv = (const float*)d_in[4];
  const float* Wo = (const float*)d_in[5];
  const float* bo = (const float*)d_in[6];
  const float* ga = (const float*)d_in[7];
  const float* be = (const float*)d_in[8];
  const float* mm = (const float*)d_in[9];
  const float* mv = (const float*)d_in[10];
  float* out = (float*)d_out;

  char* ws = (char*)d_ws;
  _Float16* xh  = (_Float16*)(ws + 0);           // 16 MB (dead after proj)
  _Float16* xl  = (_Float16*)(ws + 16777216);    // 16 MB (dead after projQK)
  _Float16* Vh  = (_Float16*)(ws + 16777216);    // overlays xl (projV output)
  _Float16* Qhi = (_Float16*)(ws + 33554432);    // 16 MB
  _Float16* Qlo = (_Float16*)(ws + 50331648);    // 16 MB
  _Float16* Khi = (_Float16*)(ws + 67108864);    // 16 MB
  _Float16* Klo = (_Float16*)(ws + 83886080);    // 16 MB
  _Float16* Wqh = (_Float16*)(ws + 100663296);   // 2 MB
  _Float16* Wql = (_Float16*)(ws + 102760448);   // 2 MB
  _Float16* Wkh = (_Float16*)(ws + 104857600);   // 2 MB
  _Float16* Wkl = (_Float16*)(ws + 106954752);   // 2 MB
  _Float16* Wvh = (_Float16*)(ws + 109051904);   // 2 MB (ends 106 MB)
  // region A (overlays dead xh after proj):
  _Float16* Woh = (_Float16*)(ws + 0);           // 2 MB
  int* klist    = (int*)(ws + 2097152);          // 32 KB
  int* cntp     = (int*)(ws + 2129920);          // 128 B
  int* cntn     = (int*)(ws + 2130048);          // 128 B
  int* idx      = (int*)(ws + 2130176);          // 512 KB
  int* ambr     = (int*)(ws + 2654464);          // 512 KB
  int* ambc     = (int*)(ws + 3178752);          // 128 B
  int* ccnt     = (int*)(ws + 3178880);          // 512 KB
  int* cnd      = (int*)(ws + 3703168);          // 4 MB (ends ~7.9 MB)

  wtrans_kernel<<<dim3(16, 16, 3), 256, 0, stream>>>(Wq, Wk, Wv, Wo,
      Wqh, Wql, Wkh, Wkl, Wvh, Woh, 0);                    // z=0..2 (no Woh)
  xcast_kernel<<<4096, 256, 0, stream>>>(x, xh, xl);
  proj_mfma<<<dim3(64, 8, 2), 256, 0, stream>>>(xh, xl, Wqh, Wql, Wkh, Wkl,
      Wvh, Qhi, Qlo, Khi, Klo, Vh, 0);                     // z=0,1 (Q,K)
  proj_mfma<<<dim3(64, 8, 1), 256, 0, stream>>>(xh, xl, Wqh, Wql, Wkh, Wkl,
      Wvh, Qhi, Qlo, Khi, Klo, Vh, 2);                     // z=2 (V over xl)
  wtrans_kernel<<<dim3(16, 16, 1), 256, 0, stream>>>(Wq, Wk, Wv, Wo,
      Wqh, Wql, Wkh, Wkl, Wvh, Woh, 3);                    // Woh into region A
  scan_kernel<<<BB, 256, 0, stream>>>(mask, klist, cntp, cntn);
  hipMemsetAsync(ambc, 0, 4, stream);
  filter_kernel<<<1024, 256, 0, stream>>>(Qhi, Qlo, Khi, klist, cntp, cntn,
                                          idx, ambr, ambc, cnd, ccnt);
  refine_kernel<<<1024, 256, 0, stream>>>(Qhi, Qlo, Khi, Klo, x, Wq, Wk,
                                          ambr, ambc, cnd, ccnt, idx);
  out_mfma<<<dim3(64, 8), 256, 0, stream>>>(Vh, idx, Woh, bo, ga, be, mm, mv, out);
}

// Round 16
// 336.806 us; speedup vs baseline: 1.0927x; 1.0927x over previous
//
#include <hip/hip_runtime.h>
#include <hip/hip_bf16.h>
#include <float.h>

#define BB 4
#define SS 2048
#define DD 1024
#define HH 16
#define DP 64
#define BKS 32
#define MARGIN_F 0.025f  /* >= 2x(packing 3.9e-3 + 2-pass filter 3sig 2.2e-3) */
#define TIER2_TAU 1e-4   /* recon-gap below this -> ground-truth re-adjudication */

typedef __attribute__((ext_vector_type(8))) _Float16 half8v;
typedef __attribute__((ext_vector_type(16))) float f32x16;

typedef __attribute__((address_space(3))) void lds_void;
typedef const __attribute__((address_space(1))) void gbl_void;
static __device__ __forceinline__ void gload16(const void* g, void* l) {
  __builtin_amdgcn_global_load_lds((gbl_void*)g, (lds_void*)l, 16, 0, 0);
}

// ---------------------------------------------------------------------------
// Prep: transpose W[k][n] f32 -> Wt[n][k] fp16 hi (+ fp16 lo residual for
// Wq,Wk).  z: 0=Wq(hi+lo) 1=Wk(hi+lo) 2=Wv(hi) 3=Wo(hi).
// ---------------------------------------------------------------------------
__global__ __launch_bounds__(256) void wtrans_kernel(
    const float* __restrict__ Wq, const float* __restrict__ Wk,
    const float* __restrict__ Wv, const float* __restrict__ Wo,
    _Float16* __restrict__ Wqh, _Float16* __restrict__ Wql,
    _Float16* __restrict__ Wkh, _Float16* __restrict__ Wkl,
    _Float16* __restrict__ Wvh, _Float16* __restrict__ Woh)
{
  const int z = blockIdx.z;
  const float* __restrict__ src = (z == 0) ? Wq : (z == 1 ? Wk : (z == 2 ? Wv : Wo));
  _Float16* __restrict__ dh = (z == 0) ? Wqh : (z == 1 ? Wkh : (z == 2 ? Wvh : Woh));
  _Float16* __restrict__ dl = (z == 0) ? Wql : Wkl;
  __shared__ float tile[64][65];
  const int k0 = blockIdx.x * 64, n0 = blockIdx.y * 64;
  const int c = threadIdx.x & 63, rb = threadIdx.x >> 6;
  #pragma unroll
  for (int i = 0; i < 16; ++i)
    tile[rb + 4 * i][c] = src[(size_t)(k0 + rb + 4 * i) * DD + n0 + c];
  __syncthreads();
  #pragma unroll
  for (int i = 0; i < 16; ++i) {
    const int n = n0 + rb + 4 * i;
    const float v = tile[c][rb + 4 * i];
    const _Float16 h = (_Float16)v;
    dh[(size_t)n * DD + k0 + c] = h;
    if (z < 2) dl[(size_t)n * DD + k0 + c] = (_Float16)(v - (float)h);
  }
}

// ---------------------------------------------------------------------------
// LDS-staged fp16 MFMA projection GEMM, 3-pass split (r10/r14 version:
// 166 us, MfmaUtil 32%, on-the-fly A split, single launch z=0..2).
// ---------------------------------------------------------------------------
__global__ __launch_bounds__(256) void proj_mfma(
    const float* __restrict__ x,
    const _Float16* __restrict__ Wqh, const _Float16* __restrict__ Wql,
    const _Float16* __restrict__ Wkh, const _Float16* __restrict__ Wkl,
    const _Float16* __restrict__ Wvh,
    _Float16* __restrict__ Qhi, _Float16* __restrict__ Qlo,
    _Float16* __restrict__ Khi, _Float16* __restrict__ Klo,
    _Float16* __restrict__ Vh)
{
  const int z = blockIdx.z;
  const bool split = (z < 2);
  const _Float16* __restrict__ Wh = (z == 0) ? Wqh : (z == 1 ? Wkh : Wvh);
  const _Float16* __restrict__ Wl = (z == 0) ? Wql : Wkl;
  _Float16* __restrict__ dhi = (z == 0) ? Qhi : (z == 1 ? Khi : Vh);
  _Float16* __restrict__ dlo = (z == 0) ? Qlo : Klo;

  __shared__ _Float16 Asm[8192];
  __shared__ _Float16 Bsm[8192];

  const int rows0 = blockIdx.x * 128, cols0 = blockIdx.y * 128;
  const int t = threadIdx.x;
  const int wid = t >> 6, l = t & 63;
  const int warpR = wid >> 1, warpC = wid & 1;
  const int lr = l & 31, lh = l >> 5;

  f32x16 acc[2][2];
  #pragma unroll
  for (int i = 0; i < 2; ++i)
    #pragma unroll
    for (int j = 0; j < 2; ++j)
      #pragma unroll
      for (int r = 0; r < 16; ++r) acc[i][j][r] = 0.f;

  const int arow = t >> 1;
  const int kc0 = (t & 1) * 2;
  const float* xsrc = x + (size_t)(rows0 + arow) * DD + kc0 * 8;
  int aslot_h0, aslot_h1, aslot_l0, aslot_l1;
  if (split) {
    aslot_h0 = arow * 8 + ((2 * kc0) ^ (arow & 7));
    aslot_h1 = arow * 8 + ((2 * kc0 + 2) ^ (arow & 7));
    aslot_l0 = arow * 8 + ((2 * kc0 + 1) ^ (arow & 7));
    aslot_l1 = arow * 8 + ((2 * kc0 + 3) ^ (arow & 7));
  } else {
    aslot_h0 = arow * 4 + (kc0 ^ ((arow >> 1) & 3));
    aslot_h1 = arow * 4 + ((kc0 + 1) ^ ((arow >> 1) & 3));
    aslot_l0 = aslot_l1 = 0;
  }

  const int nbi = split ? 4 : 2;
  const _Float16* bsrc[4];
  #pragma unroll
  for (int i = 0; i < 4; ++i) {
    const int s = t + i * 256;
    int col, wsrc; const _Float16* base;
    if (split) {
      col = s >> 3;
      const int u = (s & 7) ^ (col & 7);
      wsrc = u >> 1;
      base = (u & 1) ? Wl : Wh;
    } else {
      col = (s & 511) >> 2;
      wsrc = (s & 3) ^ ((col >> 1) & 3);
      base = Wh;
    }
    bsrc[i] = base + (size_t)(cols0 + col) * DD + wsrc * 8;
  }

  for (int ks = 0; ks < 32; ++ks) {
    const int k0 = ks * BKS;
    if (ks) __syncthreads();

    #pragma unroll
    for (int i = 0; i < 4; ++i)
      if (i < nbi) gload16(bsrc[i] + k0, &Bsm[(t + i * 256) * 8]);

    {
      const float4 f0 = *(const float4*)(xsrc + k0);
      const float4 f1 = *(const float4*)(xsrc + k0 + 4);
      const float4 f2 = *(const float4*)(xsrc + k0 + 8);
      const float4 f3 = *(const float4*)(xsrc + k0 + 12);
      const float xv[16] = {f0.x, f0.y, f0.z, f0.w, f1.x, f1.y, f1.z, f1.w,
                            f2.x, f2.y, f2.z, f2.w, f3.x, f3.y, f3.z, f3.w};
      half8v h0, h1, lo0, lo1;
      #pragma unroll
      for (int j = 0; j < 8; ++j) {
        h0[j] = (_Float16)xv[j];
        lo0[j] = (_Float16)(xv[j] - (float)h0[j]);
        h1[j] = (_Float16)xv[8 + j];
        lo1[j] = (_Float16)(xv[8 + j] - (float)h1[j]);
      }
      *(half8v*)&Asm[aslot_h0 * 8] = h0;
      *(half8v*)&Asm[aslot_h1 * 8] = h1;
      if (split) {
        *(half8v*)&Asm[aslot_l0 * 8] = lo0;
        *(half8v*)&Asm[aslot_l1 * 8] = lo1;
      }
    }
    __syncthreads();

    #pragma unroll
    for (int kh2 = 0; kh2 < 2; ++kh2) {
      const int c = kh2 * 2 + lh;
      half8v ah[2], alv[2], bh[2], blv[2];
      #pragma unroll
      for (int wr = 0; wr < 2; ++wr) {
        const int row = warpR * 64 + wr * 32 + lr;
        if (split) {
          ah[wr]  = *(const half8v*)&Asm[(row * 8 + ((2 * c) ^ (row & 7))) * 8];
          alv[wr] = *(const half8v*)&Asm[(row * 8 + ((2 * c + 1) ^ (row & 7))) * 8];
        } else {
          ah[wr] = *(const half8v*)&Asm[(row * 4 + (c ^ ((row >> 1) & 3))) * 8];
        }
      }
      #pragma unroll
      for (int wc = 0; wc < 2; ++wc) {
        const int col = warpC * 64 + wc * 32 + lr;
        if (split) {
          bh[wc]  = *(const half8v*)&Bsm[(col * 8 + ((2 * c) ^ (col & 7))) * 8];
          blv[wc] = *(const half8v*)&Bsm[(col * 8 + ((2 * c + 1) ^ (col & 7))) * 8];
        } else {
          bh[wc] = *(const half8v*)&Bsm[(col * 4 + (c ^ ((col >> 1) & 3))) * 8];
        }
      }
      #pragma unroll
      for (int wr = 0; wr < 2; ++wr)
        #pragma unroll
        for (int wc = 0; wc < 2; ++wc) {
          acc[wr][wc] = __builtin_amdgcn_mfma_f32_32x32x16_f16(ah[wr], bh[wc], acc[wr][wc], 0, 0, 0);
          if (split) {
            acc[wr][wc] = __builtin_amdgcn_mfma_f32_32x32x16_f16(alv[wr], bh[wc], acc[wr][wc], 0, 0, 0);
            acc[wr][wc] = __builtin_amdgcn_mfma_f32_32x32x16_f16(ah[wr], blv[wc], acc[wr][wc], 0, 0, 0);
          }
        }
    }
  }

  const int mb0 = rows0 + warpR * 64 + 4 * lh;
  #pragma unroll
  for (int wr = 0; wr < 2; ++wr)
    #pragma unroll
    for (int wc = 0; wc < 2; ++wc) {
      const int n = cols0 + warpC * 64 + wc * 32 + lr;
      const int h = n >> 6, d = n & 63;
      #pragma unroll
      for (int r = 0; r < 16; ++r) {
        const int m = mb0 + wr * 32 + (r & 3) + 8 * (r >> 2);
        const int b = m >> 11, srow = m & 2047;
        const size_t o = ((size_t)(b * HH + h) * SS + srow) * DP + d;
        const float a = acc[wr][wc][r];
        const _Float16 h16 = (_Float16)a;
        dhi[o] = h16;
        if (split) dlo[o] = (_Float16)(a - (float)h16);
      }
    }
}

// ---------------------------------------------------------------------------
// Mask scan -> compact key list padded to x32 with duplicates of the first
// masked key; writes real count (for validity masking) and padded count.
// ---------------------------------------------------------------------------
__global__ __launch_bounds__(256) void scan_kernel(
    const int* __restrict__ mask, int* __restrict__ klist,
    int* __restrict__ cntpad, int* __restrict__ cntreal)
{
  __shared__ int part[256];
  __shared__ int tot;
  const int b = blockIdx.x, t = threadIdx.x;
  int loc[8]; int c = 0;
  #pragma unroll
  for (int j = 0; j < 8; ++j) {
    loc[j] = (mask[(b << 11) + t * 8 + j] == 0);
    c += loc[j];
  }
  part[t] = c;
  __syncthreads();
  if (t == 0) {
    int run = 0;
    for (int i = 0; i < 256; ++i) { int v = part[i]; part[i] = run; run += v; }
    tot = run;
  }
  __syncthreads();
  int off = part[t];
  #pragma unroll
  for (int j = 0; j < 8; ++j)
    if (loc[j]) klist[(b << 11) + off++] = t * 8 + j;
  __syncthreads();
  if (t == 0) {
    int n = tot;
    int first;
    if (n == 0) { klist[b << 11] = 0; n = 1; first = 0; }
    else first = klist[b << 11];
    int np = (n + 31) & ~31;
    for (int i = n; i < np; ++i) klist[(b << 11) + i] = first;
    cntpad[b] = np;
    cntreal[b] = n;
  }
}

// ---------------------------------------------------------------------------
// MFMA masked-argmin filter, 2-pass, LDS-staged Khi, HIERARCHICAL selection:
// per-tile top-2 (2 ops/score) merged into row top-4 (7 ops/tile) -- cuts
// the per-score fmed3 chain from 4 to 1 (filter was VALU-bound).
// Capture guarantee: a margin-mate misses the tile top-2 only if >=3
// margin-mates share one 32-key tile (P ~ 1e-8 rows); t2>=m1 always after
// t1's insertion, so the merge needs no m1 update for t2.
// ---------------------------------------------------------------------------
__global__ __launch_bounds__(256) void filter_kernel(
    const _Float16* __restrict__ Qhi, const _Float16* __restrict__ Qlo,
    const _Float16* __restrict__ Khi,
    const int* __restrict__ klist, const int* __restrict__ cntpad,
    const int* __restrict__ cntreal,
    int* __restrict__ idx, int* __restrict__ ambr, int* __restrict__ ambc,
    int* __restrict__ cand, int* __restrict__ ccnt)
{
  __shared__ _Float16 Ksm[2048];   // 4 KB
  const int bh = blockIdx.x >> 4;
  const int b = bh >> 4;
  const int wid = threadIdx.x >> 6;
  const int t = threadIdx.x;
  const int l = t & 63;
  const int q0 = ((blockIdx.x & 15) << 7) + (wid << 5);
  const int half = l >> 5;
  const int lq = l & 31;
  const int* __restrict__ kl_b = klist + (b << 11);

  half8v qh[4], ql[4];
  {
    const size_t qrow = ((size_t)bh * SS + q0 + lq) * DP + half * 8;
    #pragma unroll
    for (int ds = 0; ds < 4; ++ds) {
      qh[ds] = *(const half8v*)(Qhi + qrow + ds * 16);
      ql[ds] = *(const half8v*)(Qlo + qrow + ds * 16);
    }
  }

  const int srow = t >> 3;
  const int sslot = t & 7;
  const int scc = sslot ^ (srow & 7);

  const int nreal = cntreal[b];
  const int nt = cntpad[b] >> 5;
  float m1 = FLT_MAX, m2 = FLT_MAX, m3 = FLT_MAX, m4 = FLT_MAX;
  uint kidx[16];
  #pragma unroll
  for (int r = 0; r < 16; ++r)
    kidx[r] = (uint)((r & 3) + ((r >> 2) << 3) + (half << 2));

  const size_t kbase = (size_t)bh * SS;
  for (int kt = 0; kt < nt; ++kt) {
    if (kt) __syncthreads();
    {
      const int kval = kl_b[(kt << 5) + srow];
      gload16(Khi + (kbase + kval) * DP + scc * 8, &Ksm[t * 8]);
    }
    __syncthreads();

    f32x16 acc;
    #pragma unroll
    for (int r = 0; r < 16; ++r) acc[r] = 0.f;
    #pragma unroll
    for (int ds = 0; ds < 4; ++ds) {
      const int cc = ds * 2 + half;
      const int sl = lq * 8 + (cc ^ (lq & 7));
      const half8v kh = *(const half8v*)&Ksm[sl * 8];
      acc = __builtin_amdgcn_mfma_f32_32x32x16_f16(kh, qh[ds], acc, 0, 0, 0);
      acc = __builtin_amdgcn_mfma_f32_32x32x16_f16(kh, ql[ds], acc, 0, 0, 0);
    }

    float t1 = FLT_MAX, t2 = FLT_MAX;
    if (kt < nt - 1 || (nreal & 31) == 0) {
      #pragma unroll
      for (int r = 0; r < 16; ++r) {
        const float v = __uint_as_float(
            (__float_as_uint(acc[r]) & 0xFFFFF800u) | kidx[r]);
        t2 = __builtin_amdgcn_fmed3f(v, t1, t2);
        t1 = fminf(v, t1);
        kidx[r] += 32;
      }
    } else {
      #pragma unroll
      for (int r = 0; r < 16; ++r) {
        float v = __uint_as_float(
            (__float_as_uint(acc[r]) & 0xFFFFF800u) | kidx[r]);
        if (kidx[r] >= (uint)nreal) v = FLT_MAX;   // padded: never competes
        t2 = __builtin_amdgcn_fmed3f(v, t1, t2);
        t1 = fminf(v, t1);
        kidx[r] += 32;
      }
    }
    // merge tile top-2 into row top-4 (t2 >= m1 after t1's insertion)
    m4 = __builtin_amdgcn_fmed3f(t1, m3, m4);
    m3 = __builtin_amdgcn_fmed3f(t1, m2, m3);
    m2 = __builtin_amdgcn_fmed3f(t1, m1, m2);
    m1 = fminf(t1, m1);
    m4 = __builtin_amdgcn_fmed3f(t2, m3, m4);
    m3 = __builtin_amdgcn_fmed3f(t2, m2, m3);
    m2 = __builtin_amdgcn_fmed3f(t2, m1, m2);
  }

  float om[4];
  om[0] = __shfl_xor(m1, 32, 64);
  om[1] = __shfl_xor(m2, 32, 64);
  om[2] = __shfl_xor(m3, 32, 64);
  om[3] = __shfl_xor(m4, 32, 64);
  #pragma unroll
  for (int j = 0; j < 4; ++j) {
    const float v = om[j];
    m4 = __builtin_amdgcn_fmed3f(v, m3, m4);
    m3 = __builtin_amdgcn_fmed3f(v, m2, m3);
    m2 = __builtin_amdgcn_fmed3f(v, m1, m2);
    m1 = fminf(v, m1);
  }

  if (half == 0) {
    const int row = bh * SS + q0 + lq;
    const uint u1 = __float_as_uint(m1);
    const int k1 = kl_b[u1 & 2047u];
    idx[row] = k1;
    const float v1 = __uint_as_float(u1 & 0xFFFFF800u);
    const uint us[3] = {__float_as_uint(m2), __float_as_uint(m3),
                        __float_as_uint(m4)};
    const float v2 = __uint_as_float(us[0] & 0xFFFFF800u);
    if (v2 - v1 < MARGIN_F) {
      int c[4]; int n = 0;
      c[n++] = k1;
      #pragma unroll
      for (int j = 0; j < 3; ++j) {
        const float vj = __uint_as_float(us[j] & 0xFFFFF800u);
        if (vj - v1 < MARGIN_F) c[n++] = kl_b[us[j] & 2047u];
        else break;
      }
      const int pos = atomicAdd(ambc, 1);
      ambr[pos] = row;
      ccnt[row] = n;
      for (int j = 0; j < n; ++j) cand[row * 8 + j] = c[j];
    }
  }
}

// ---------------------------------------------------------------------------
// Two-tier refine (r9/r10 version, verbatim).
// ---------------------------------------------------------------------------
__global__ __launch_bounds__(256) void refine_kernel(
    const _Float16* __restrict__ Qhi, const _Float16* __restrict__ Qlo,
    const _Float16* __restrict__ Khi, const _Float16* __restrict__ Klo,
    const float* __restrict__ x, const float* __restrict__ Wq,
    const float* __restrict__ Wk,
    const int* __restrict__ ambr, const int* __restrict__ ambc,
    const int* __restrict__ cand, const int* __restrict__ ccnt,
    int* __restrict__ idx)
{
  __shared__ double red[4][7][64];
  const int n = *ambc;
  const int t = threadIdx.x;
  const int w = t >> 6, lane = t & 63;

  for (int it = blockIdx.x; it < n; it += gridDim.x) {
    const int row = ambr[it];
    const int bh = row >> 11;
    const int cnum = ccnt[row];

    const size_t qb = (size_t)row * DP;
    const double q = (double)(float)Qhi[qb + lane] + (double)(float)Qlo[qb + lane];
    double best = 1e300, best2 = 1e300; int bi = 0x7fffffff;
    for (int c = 0; c < cnum; ++c) {
      const int k = cand[row * 8 + c] & 2047;
      const size_t kb = ((size_t)bh * SS + k) * DP;
      const double kv = (double)(float)Khi[kb + lane] + (double)(float)Klo[kb + lane];
      double p = q * kv;
      #pragma unroll
      for (int o = 32; o > 0; o >>= 1) p += __shfl_xor(p, o, 64);
      if (p < best) { best2 = best; best = p; bi = k; }
      else if (p < best2) best2 = p;
    }

    if (best2 - best < TIER2_TAU) {
      const int qq = row & 2047;
      const int b = bh >> 4, h = bh & 15;
      const int wc = (h << 6) + lane;
      const float* xq = x + ((size_t)(b << 11) + qq) * DD;
      int kk[6];
      #pragma unroll
      for (int c = 0; c < 6; ++c)
        kk[c] = cand[row * 8 + (c < cnum ? c : 0)] & 2047;
      const float* xk0 = x + ((size_t)(b << 11) + kk[0]) * DD;
      const float* xk1 = x + ((size_t)(b << 11) + kk[1]) * DD;
      const float* xk2 = x + ((size_t)(b << 11) + kk[2]) * DD;
      const float* xk3 = x + ((size_t)(b << 11) + kk[3]) * DD;
      const float* xk4 = x + ((size_t)(b << 11) + kk[4]) * DD;
      const float* xk5 = x + ((size_t)(b << 11) + kk[5]) * DD;

      double qd = 0.0, kd0 = 0.0, kd1 = 0.0, kd2 = 0.0,
             kd3 = 0.0, kd4 = 0.0, kd5 = 0.0;
      const int j0 = w * 256;
      #pragma unroll 4
      for (int j = j0; j < j0 + 256; ++j) {
        const double wq = (double)Wq[(size_t)j * DD + wc];
        const double wk = (double)Wk[(size_t)j * DD + wc];
        qd  = fma((double)xq[j],  wq, qd);
        kd0 = fma((double)xk0[j], wk, kd0);
        kd1 = fma((double)xk1[j], wk, kd1);
        kd2 = fma((double)xk2[j], wk, kd2);
        kd3 = fma((double)xk3[j], wk, kd3);
        kd4 = fma((double)xk4[j], wk, kd4);
        kd5 = fma((double)xk5[j], wk, kd5);
      }
      red[w][0][lane] = qd;
      red[w][1][lane] = kd0; red[w][2][lane] = kd1; red[w][3][lane] = kd2;
      red[w][4][lane] = kd3; red[w][5][lane] = kd4; red[w][6][lane] = kd5;
      __syncthreads();

      if (w == 0) {
        const double qs = red[0][0][lane] + red[1][0][lane] +
                          red[2][0][lane] + red[3][0][lane];
        best = 1e300; bi = 0x7fffffff;
        for (int c = 0; c < cnum; ++c) {
          const double ks = red[0][1 + c][lane] + red[1][1 + c][lane] +
                            red[2][1 + c][lane] + red[3][1 + c][lane];
          double p = qs * ks;
          #pragma unroll
          for (int o = 32; o > 0; o >>= 1) p += __shfl_xor(p, o, 64);
          const int k = kk[c];
          if (p < best || (p == best && k < bi)) { best = p; bi = k; }
        }
        if (lane == 0) idx[row] = bi;
      }
      __syncthreads();
    } else {
      if (t == 0) idx[row] = bi;
    }
  }
}

// ---------------------------------------------------------------------------
// fp16 MFMA out-projection, LDS-staged B (r11/r12 version).
// ---------------------------------------------------------------------------
__global__ __launch_bounds__(256) void out_mfma(
    const _Float16* __restrict__ Vh, const int* __restrict__ idx,
    const _Float16* __restrict__ Woh, const float* __restrict__ bo,
    const float* __restrict__ gamma, const float* __restrict__ beta,
    const float* __restrict__ mmean, const float* __restrict__ mvar,
    float* __restrict__ out)
{
  __shared__ _Float16 Bsm[8192];
  const int rows0 = blockIdx.x * 128, cols0 = blockIdx.y * 128;
  const int t = threadIdx.x;
  const int w = t >> 6, l = t & 63;
  const int lr = l & 31, lh = l >> 5;
  const int hi8 = lh * 8;
  const int m = rows0 + w * 32 + lr;
  const int b = m >> 11, srow = m & 2047;

  const _Float16* bsrc[4];
  #pragma unroll
  for (int i = 0; i < 4; ++i) {
    const int s = t + i * 256;
    const int col = s >> 3;
    const int u = (s & 7) ^ (col & 7);
    bsrc[i] = Woh + (size_t)(cols0 + col) * DD + u * 8;
  }

  f32x16 acc[4];
  #pragma unroll
  for (int cf = 0; cf < 4; ++cf)
    #pragma unroll
    for (int r = 0; r < 16; ++r) acc[cf][r] = 0.f;

  for (int kt = 0; kt < 16; ++kt) {
    const int k0 = kt * 64;
    if (kt) __syncthreads();
    #pragma unroll
    for (int i = 0; i < 4; ++i)
      gload16(bsrc[i] + k0, &Bsm[(t + i * 256) * 8]);
    const int vi = idx[(size_t)(b * HH + kt) * SS + srow];
    const _Float16* arow = Vh + ((size_t)(b * HH + kt) * SS + vi) * DP;
    __syncthreads();

    #pragma unroll
    for (int ss = 0; ss < 4; ++ss) {
      half8v a = *(const half8v*)(arow + ss * 16 + hi8);
      const int cl = ss * 2 + lh;
      #pragma unroll
      for (int cf = 0; cf < 4; ++cf) {
        const int col = cf * 32 + lr;
        half8v bf = *(const half8v*)&Bsm[(col * 8 + (cl ^ (col & 7))) * 8];
        acc[cf] = __builtin_amdgcn_mfma_f32_32x32x16_f16(a, bf, acc[cf], 0, 0, 0);
      }
    }
  }

  const int m_base = rows0 + w * 32 + 4 * lh;
  #pragma unroll
  for (int cf = 0; cf < 4; ++cf) {
    const int n = cols0 + cf * 32 + lr;
    const float sc = gamma[n] * rsqrtf(mvar[n] + 1e-3f);
    const float ofs = (bo[n] - mmean[n]) * sc + beta[n];
    #pragma unroll
    for (int r = 0; r < 16; ++r) {
      const int mr = m_base + (r & 3) + 8 * (r >> 2);
      out[(size_t)mr * DD + n] = acc[cf][r] * sc + ofs;
    }
  }
}

// ---------------------------------------------------------------------------
extern "C" void kernel_launch(void* const* d_in, const int* in_sizes, int n_in,
                              void* d_out, int out_size, void* d_ws, size_t ws_size,
                              hipStream_t stream)
{
  const float* x  = (const float*)d_in[0];
  const int* mask = (const int*)d_in[1];
  const float* Wq = (const float*)d_in[2];
  const float* Wk = (const float*)d_in[3];
  const float* Wv = (const float*)d_in[4];
  const float* Wo = (const float*)d_in[5];
  const float* bo = (const float*)d_in[6];
  const float* ga = (const float*)d_in[7];
  const float* be = (const float*)d_in[8];
  const float* mm = (const float*)d_in[9];
  const float* mv = (const float*)d_in[10];
  float* out = (float*)d_out;

  char* ws = (char*)d_ws;
  _Float16* Qhi = (_Float16*)(ws + 0);          // 16 MB
  _Float16* Qlo = (_Float16*)(ws + 16777216);   // 16 MB
  _Float16* Khi = (_Float16*)(ws + 33554432);   // 16 MB
  _Float16* Klo = (_Float16*)(ws + 50331648);   // 16 MB
  _Float16* Vh  = (_Float16*)(ws + 67108864);   // 16 MB
  _Float16* Wqh = (_Float16*)(ws + 83886080);   // 2 MB
  _Float16* Wql = (_Float16*)(ws + 85983232);   // 2 MB
  _Float16* Wkh = (_Float16*)(ws + 88080384);   // 2 MB
  _Float16* Wkl = (_Float16*)(ws + 90177536);   // 2 MB
  _Float16* Wvh = (_Float16*)(ws + 92274688);   // 2 MB
  _Float16* Woh = (_Float16*)(ws + 94371840);   // 2 MB
  int* klist    = (int*)(ws + 96468992);        // 32 KB
  int* cntp     = (int*)(ws + 96501760);        // 128 B
  int* cntn     = (int*)(ws + 96501888);        // 128 B
  int* idx      = (int*)(ws + 96502016);        // 512 KB
  int* ambr     = (int*)(ws + 97026304);        // 512 KB
  int* ambc     = (int*)(ws + 97550592);        // 128 B
  int* ccnt     = (int*)(ws + 97550720);        // 512 KB
  int* cnd      = (int*)(ws + 98075008);        // 4 MB (end ~97.5 MB)

  hipMemsetAsync(ambc, 0, 4, stream);
  wtrans_kernel<<<dim3(16, 16, 4), 256, 0, stream>>>(Wq, Wk, Wv, Wo,
                                                     Wqh, Wql, Wkh, Wkl, Wvh, Woh);
  scan_kernel<<<BB, 256, 0, stream>>>(mask, klist, cntp, cntn);
  proj_mfma<<<dim3(64, 8, 3), 256, 0, stream>>>(x, Wqh, Wql, Wkh, Wkl, Wvh,
                                                Qhi, Qlo, Khi, Klo, Vh);
  filter_kernel<<<1024, 256, 0, stream>>>(Qhi, Qlo, Khi, klist, cntp, cntn,
                                          idx, ambr, ambc, cnd, ccnt);
  refine_kernel<<<1024, 256, 0, stream>>>(Qhi, Qlo, Khi, Klo, x, Wq, Wk,
                                          ambr, ambc, cnd, ccnt, idx);
  out_mfma<<<dim3(64, 8), 256, 0, stream>>>(Vh, idx, Woh, bo, ga, be, mm, mv, out);
}